// Round 1
// baseline (2839.666 us; speedup 1.0000x reference)
//
#include <hip/hip_runtime.h>
#include <hip/hip_bf16.h>

// VisionExpertMLP: two 2048-token SwiGLU MLPs (lang rows 0..2047, vis rows 2048..4095).
// gemm1 (per expert): gu = x(2048x4096) @ Wgu(4096x22016); h = silu(gu[:, :11008]) * gu[:, 11008:]
//   -> h stored bf16 in d_ws (2048x11008).
// gemm2: out = h @ Wd(11008x4096) -> fp32 d_out rows [e*2048, e*2048+2048).
// bf16 MFMA 16x16x32, fp32 accum. On-the-fly fp32->bf16 RNE conversion during reg-staging.
// LDS tiles [rows][64] bf16 with rotation swizzle pos=((k>>3)+(r>>2)+2*(r&3))&7 so both
// fragment reads (row stride 1) and transpose-staging writes (row stride 4) are spread
// across all 8 16B positions of the 128B row.

#define HDIM 4096
#define IDIM 11008
#define N2   22016
#define MTOK 2048
#define BM   128
#define BN   128
#define BK   64

using f32x4  = __attribute__((ext_vector_type(4))) float;
using bf16x8 = __attribute__((ext_vector_type(8))) short;
using u32x2  = __attribute__((ext_vector_type(2))) unsigned int;
using u32x4  = __attribute__((ext_vector_type(4))) unsigned int;

__device__ __forceinline__ unsigned int bf16rne(float f) {
    unsigned int u = __builtin_bit_cast(unsigned int, f);
    return (u + 0x7FFFu + ((u >> 16) & 1u)) >> 16;
}
__device__ __forceinline__ unsigned int pack2(float lo, float hi) {
    return bf16rne(lo) | (bf16rne(hi) << 16);
}
// per-row rotation for the 8 16B-positions of a 128B LDS row
__device__ __forceinline__ int swz(int r) { return ((r >> 2) + ((r & 3) << 1)) & 7; }

// ---------------- GEMM1: fused gate/up + silu ----------------
__global__ __launch_bounds__(256, 2)
void gu_kernel(const float* __restrict__ X, const float* __restrict__ W,
               unsigned short* __restrict__ Hbuf) {
    __shared__ short As[BM * BK];
    __shared__ short Bg[BN * BK];
    __shared__ short Bu[BN * BK];

    // XCD-aware block swizzle (gridDim.x % 8 == 0), m-fastest so neighbors share W panel
    int nwg = gridDim.x;
    int cpx = nwg >> 3;
    int sw  = (blockIdx.x & 7) * cpx + (blockIdx.x >> 3);
    int mblk = sw & 15;          // MTOK/BM = 16
    int nblk = sw >> 4;          // 0..85
    const int m0 = mblk * BM;
    const int n0 = nblk * BN;

    const int t    = threadIdx.x;
    const int lane = t & 63;
    const int w    = t >> 6;
    const int wm   = w >> 1, wn = w & 1;
    const int rr   = lane & 15, g4 = lane >> 4;

    // B staging mapping: 8k x 4n micro-tile per thread
    const int nc = t & 31;   // n-chunk of 4
    const int kc = t >> 5;   // k-chunk of 8 (0..7)

    f32x4 accg[4][4] = {};
    f32x4 accu[4][4] = {};

    for (int k0 = 0; k0 < HDIM; k0 += BK) {
        __syncthreads();
        // ---- stage A: x[m0..m0+127][k0..k0+63] fp32 -> bf16 ----
#pragma unroll
        for (int i = 0; i < 8; ++i) {
            int idx = t + i * 256;
            int m = idx >> 4, c4 = idx & 15;
            const float* p = X + (long)(m0 + m) * HDIM + k0 + c4 * 4;
            f32x4 v = *(const f32x4*)p;
            u32x2 pk = { pack2(v[0], v[1]), pack2(v[2], v[3]) };
            int off = (m << 6) + ((((c4 >> 1) + swz(m)) & 7) << 3) + ((c4 & 1) << 2);
            *(u32x2*)&As[off] = pk;
        }
        // ---- stage Bg/Bu: W[k0..k0+63][cols] fp32 -> bf16, transposed to [n][k] ----
#pragma unroll
        for (int e = 0; e < 2; ++e) {
            const float* Wp = W + (long)(k0 + kc * 8) * N2 + (e ? (IDIM + n0) : n0) + nc * 4;
            short* Bl = e ? Bu : Bg;
#pragma unroll
            for (int h = 0; h < 2; ++h) {
                f32x4 r0 = *(const f32x4*)(Wp + (long)(h * 4 + 0) * N2);
                f32x4 r1 = *(const f32x4*)(Wp + (long)(h * 4 + 1) * N2);
                f32x4 r2 = *(const f32x4*)(Wp + (long)(h * 4 + 2) * N2);
                f32x4 r3 = *(const f32x4*)(Wp + (long)(h * 4 + 3) * N2);
#pragma unroll
                for (int c = 0; c < 4; ++c) {
                    int n = nc * 4 + c;
                    u32x2 pk = { pack2(r0[c], r1[c]), pack2(r2[c], r3[c]) };
                    int off = (n << 6) + (((kc + swz(n)) & 7) << 3) + (h << 2);
                    *(u32x2*)&Bl[off] = pk;
                }
            }
        }
        __syncthreads();
        // ---- compute ----
#pragma unroll
        for (int ks = 0; ks < 2; ++ks) {
            bf16x8 a[4], bg[4], bu[4];
#pragma unroll
            for (int mf = 0; mf < 4; ++mf) {
                int r = wm * 64 + mf * 16 + rr;
                a[mf] = *(const bf16x8*)&As[(r << 6) + ((((ks * 4 + g4) + swz(r)) & 7) << 3)];
            }
#pragma unroll
            for (int nf = 0; nf < 4; ++nf) {
                int r = wn * 64 + nf * 16 + rr;
                int off = (r << 6) + ((((ks * 4 + g4) + swz(r)) & 7) << 3);
                bg[nf] = *(const bf16x8*)&Bg[off];
                bu[nf] = *(const bf16x8*)&Bu[off];
            }
#pragma unroll
            for (int mf = 0; mf < 4; ++mf)
#pragma unroll
                for (int nf = 0; nf < 4; ++nf) {
                    accg[mf][nf] = __builtin_amdgcn_mfma_f32_16x16x32_bf16(a[mf], bg[nf], accg[mf][nf], 0, 0, 0);
                    accu[mf][nf] = __builtin_amdgcn_mfma_f32_16x16x32_bf16(a[mf], bu[nf], accu[mf][nf], 0, 0, 0);
                }
        }
    }
    // ---- epilogue: silu(g)*u -> bf16 h ----
#pragma unroll
    for (int mf = 0; mf < 4; ++mf)
#pragma unroll
        for (int nf = 0; nf < 4; ++nf)
#pragma unroll
            for (int i = 0; i < 4; ++i) {
                int m = m0 + wm * 64 + mf * 16 + g4 * 4 + i;
                int n = n0 + wn * 64 + nf * 16 + rr;
                float gv = accg[mf][nf][i];
                float uv = accu[mf][nf][i];
                float s  = gv / (1.0f + __expf(-gv));
                Hbuf[(long)m * IDIM + n] = (unsigned short)bf16rne(s * uv);
            }
}

// ---------------- GEMM2: down projection ----------------
__global__ __launch_bounds__(256, 2)
void down_kernel(const unsigned short* __restrict__ Hbuf, const float* __restrict__ W,
                 float* __restrict__ Out) {
    __shared__ short As[BM * BK];
    __shared__ short Bs[BN * BK];

    int nwg = gridDim.x;
    int cpx = nwg >> 3;
    int sw  = (blockIdx.x & 7) * cpx + (blockIdx.x >> 3);
    int mblk = sw & 15;
    int nblk = sw >> 4;          // 0..31
    const int m0 = mblk * BM;
    const int n0 = nblk * BN;

    const int t    = threadIdx.x;
    const int lane = t & 63;
    const int w    = t >> 6;
    const int wm   = w >> 1, wn = w & 1;
    const int rr   = lane & 15, g4 = lane >> 4;

    const int nc = t & 31;
    const int kc = t >> 5;

    f32x4 acc[4][4] = {};

    for (int k0 = 0; k0 < IDIM; k0 += BK) {
        __syncthreads();
        // ---- stage A: h (already bf16), 16B chunks ----
#pragma unroll
        for (int i = 0; i < 4; ++i) {
            int idx = t + i * 256;
            int m = idx >> 3, kc8 = idx & 7;
            u32x4 v = *(const u32x4*)(Hbuf + (long)(m0 + m) * IDIM + k0 + kc8 * 8);
            int off = (m << 6) + (((kc8 + swz(m)) & 7) << 3);
            *(u32x4*)&As[off] = v;
        }
        // ---- stage B: Wd[k0..k0+63][n0..n0+127] fp32 -> bf16 transposed ----
        {
            const float* Wp = W + (long)(k0 + kc * 8) * HDIM + n0 + nc * 4;
#pragma unroll
            for (int h = 0; h < 2; ++h) {
                f32x4 r0 = *(const f32x4*)(Wp + (long)(h * 4 + 0) * HDIM);
                f32x4 r1 = *(const f32x4*)(Wp + (long)(h * 4 + 1) * HDIM);
                f32x4 r2 = *(const f32x4*)(Wp + (long)(h * 4 + 2) * HDIM);
                f32x4 r3 = *(const f32x4*)(Wp + (long)(h * 4 + 3) * HDIM);
#pragma unroll
                for (int c = 0; c < 4; ++c) {
                    int n = nc * 4 + c;
                    u32x2 pk = { pack2(r0[c], r1[c]), pack2(r2[c], r3[c]) };
                    int off = (n << 6) + (((kc + swz(n)) & 7) << 3) + (h << 2);
                    *(u32x2*)&Bs[off] = pk;
                }
            }
        }
        __syncthreads();
        // ---- compute ----
#pragma unroll
        for (int ks = 0; ks < 2; ++ks) {
            bf16x8 a[4], b[4];
#pragma unroll
            for (int mf = 0; mf < 4; ++mf) {
                int r = wm * 64 + mf * 16 + rr;
                a[mf] = *(const bf16x8*)&As[(r << 6) + ((((ks * 4 + g4) + swz(r)) & 7) << 3)];
            }
#pragma unroll
            for (int nf = 0; nf < 4; ++nf) {
                int r = wn * 64 + nf * 16 + rr;
                b[nf] = *(const bf16x8*)&Bs[(r << 6) + ((((ks * 4 + g4) + swz(r)) & 7) << 3)];
            }
#pragma unroll
            for (int mf = 0; mf < 4; ++mf)
#pragma unroll
                for (int nf = 0; nf < 4; ++nf)
                    acc[mf][nf] = __builtin_amdgcn_mfma_f32_16x16x32_bf16(a[mf], b[nf], acc[mf][nf], 0, 0, 0);
        }
    }
    // ---- epilogue: fp32 out ----
#pragma unroll
    for (int mf = 0; mf < 4; ++mf)
#pragma unroll
        for (int nf = 0; nf < 4; ++nf)
#pragma unroll
            for (int i = 0; i < 4; ++i) {
                int m = m0 + wm * 64 + mf * 16 + g4 * 4 + i;
                int n = n0 + wn * 64 + nf * 16 + rr;
                Out[(long)m * HDIM + n] = acc[mf][nf][i];
            }
}

extern "C" void kernel_launch(void* const* d_in, const int* in_sizes, int n_in,
                              void* d_out, int out_size, void* d_ws, size_t ws_size,
                              hipStream_t stream) {
    const float* x      = (const float*)d_in[0];
    // d_in[1], d_in[2]: lang_ids / vision_ids — fixed contiguous aranges, split by offset.
    const float* Wgu_l  = (const float*)d_in[3];
    const float* Wd_l   = (const float*)d_in[4];
    const float* Wgu_v  = (const float*)d_in[5];
    const float* Wd_v   = (const float*)d_in[6];
    float* out          = (float*)d_out;
    unsigned short* hbuf = (unsigned short*)d_ws;  // 2048*11008 bf16 = 45.1 MB, reused per expert

    for (int e = 0; e < 2; ++e) {
        const float* Wgu = e ? Wgu_v : Wgu_l;
        const float* Wd  = e ? Wd_v  : Wd_l;
        const float* xe  = x   + (long)e * MTOK * HDIM;
        float*       oe  = out + (long)e * MTOK * HDIM;
        gu_kernel<<<dim3((MTOK / BM) * (IDIM / BN)), dim3(256), 0, stream>>>(xe, Wgu, hbuf);
        down_kernel<<<dim3((MTOK / BM) * (HDIM / BN)), dim3(256), 0, stream>>>(hbuf, Wd, oe);
    }
}

// Round 2
// 1468.546 us; speedup vs baseline: 1.9337x; 1.9337x over previous
//
#include <hip/hip_runtime.h>
#include <hip/hip_bf16.h>

// VisionExpertMLP round 2: pre-convert fp32 weights/activations to bf16, TILE-PACKED
// (16KB tiles in exact staging order) with the XOR bank-swizzle baked into the pack.
// GEMMs stage via global_load_lds (width 16, linear LDS dest) and do conflict-free
// swizzled ds_read_b128 fragment reads. m97-style 128x128xBK64 single-buffer structure.
//
// Packed tile layout (128 rows x 64 k, bf16, 16384 B):
//   elem (r, k) at byte  r*128 + (((k>>3) ^ (r&7))<<4) + ((k&7)<<1)
// Fragment read (row r, k-chunk c=ks*4+g4): 16B at r*128 + ((c ^ (r&7))<<4)
//   -> 16 lanes rows r..r+15, chunk XOR spans all 8 positions => 2-way (free).
//
// ws layout: XP (16 MB, x bf16 packed, per expert) | HP (45 MB, h bf16 packed)
//            | WP (180 MB, Wgu or Wd packed, reused). Fallback to round-1 path if
//            ws_size too small.

#define HDIM 4096
#define IDIM 11008
#define N2   22016
#define MTOK 2048
#define BM   128
#define BN   128
#define BK   64
#define KT1  64      // HDIM/64
#define KT2  172     // IDIM/64
#define NB1  86      // IDIM/128
#define NB2  32      // HDIM/128

typedef unsigned short ushort_t;
using f32x4  = __attribute__((ext_vector_type(4))) float;
using bf16x8 = __attribute__((ext_vector_type(8))) short;
using u32x2  = __attribute__((ext_vector_type(2))) unsigned int;
using u32x4  = __attribute__((ext_vector_type(4))) unsigned int;

__device__ __forceinline__ unsigned int bf16rne(float f) {
    unsigned int u = __builtin_bit_cast(unsigned int, f);
    return (u + 0x7FFFu + ((u >> 16) & 1u)) >> 16;
}
__device__ __forceinline__ unsigned int pack2(float lo, float hi) {
    return bf16rne(lo) | (bf16rne(hi) << 16);
}
__device__ __forceinline__ void gl_lds16(const void* g, void* l) {
    __builtin_amdgcn_global_load_lds(
        (const __attribute__((address_space(1))) void*)g,
        (__attribute__((address_space(3))) void*)l, 16, 0, 0);
}

// ---------------- conversion kernels ----------------

// x fp32 row-major [2048][4096] -> XP packed [mb][kt][128][64]
__global__ __launch_bounds__(256)
void conv_x(const float* __restrict__ X, ushort_t* __restrict__ XP) {
    int bid = blockIdx.x;               // 16*64
    int rb = bid >> 6, kt = bid & 63;
    int t = threadIdx.x;
    int r0 = t >> 4, c4 = t & 15;
    ushort_t* tp = XP + (long)bid * 8192;
#pragma unroll
    for (int p = 0; p < 8; ++p) {
        int r = r0 + p * 16;
        f32x4 v = *(const f32x4*)(X + (long)(rb * 128 + r) * HDIM + kt * 64 + c4 * 4);
        u32x2 pk = { pack2(v[0], v[1]), pack2(v[2], v[3]) };
        int off = r * 64 + ((((c4 >> 1) ^ (r & 7)) << 3)) + ((c4 & 1) << 2);
        *(u32x2*)&tp[off] = pk;
    }
}

// W fp32 [k][n] -> packed transposed tiles [...][128 n][64 k]
// per-block: one tile. 8 f32x4 loads per thread (8 k-rows x 4 n-cols) -> 4x u32x4 writes.
__device__ __forceinline__ void conv_w_tile(const float* W, ushort_t* tp, long ld,
                                            long krow0, long col0, int t) {
    int kp = t >> 5, c4 = t & 31;
    const float* p = W + (krow0 + kp * 8) * ld + col0 + c4 * 4;
    f32x4 v[8];
#pragma unroll
    for (int j = 0; j < 8; ++j) v[j] = *(const f32x4*)(p + (long)j * ld);
#pragma unroll
    for (int c = 0; c < 4; ++c) {
        int n = c4 * 4 + c;
        u32x4 pk = { pack2(v[0][c], v[1][c]), pack2(v[2][c], v[3][c]),
                     pack2(v[4][c], v[5][c]), pack2(v[6][c], v[7][c]) };
        int off = n * 64 + ((kp ^ (n & 7)) << 3);
        *(u32x4*)&tp[off] = pk;
    }
}

// Wgu [4096][22016]: tile id = ((nb*64+kt)*2+e); cols = e*IDIM + nb*128
__global__ __launch_bounds__(256)
void conv_wgu(const float* __restrict__ W, ushort_t* __restrict__ WP) {
    int bid = blockIdx.x;               // 86*64*2
    int e = bid & 1, kt = (bid >> 1) & 63, nb = bid >> 7;
    conv_w_tile(W, WP + (long)bid * 8192, N2, (long)kt * 64,
                (long)e * IDIM + (long)nb * 128, threadIdx.x);
}

// Wd [11008][4096]: tile id = nb*172+kt
__global__ __launch_bounds__(256)
void conv_wd(const float* __restrict__ W, ushort_t* __restrict__ WP) {
    int bid = blockIdx.x;               // 32*172
    int kt = bid % KT2, nb = bid / KT2;
    conv_w_tile(W, WP + (long)bid * 8192, HDIM, (long)kt * 64,
                (long)nb * 128, threadIdx.x);
}

// ---------------- GEMM1: fused gate/up + silu ----------------
__global__ __launch_bounds__(256, 2)
void gu2_kernel(const ushort_t* __restrict__ XP, const ushort_t* __restrict__ WP,
                ushort_t* __restrict__ HP) {
    __shared__ ushort_t lds[24576];     // As(8192) | Bg(8192) | Bu(8192)

    int nwg = gridDim.x;                // 1376
    int cpx = nwg >> 3;
    int sw  = (blockIdx.x & 7) * cpx + (blockIdx.x >> 3);
    int mblk = sw & 15;
    int nblk = sw >> 4;                 // 0..85

    const int t    = threadIdx.x;
    const int lane = t & 63;
    const int w    = t >> 6;
    const int wm   = w >> 1, wn = w & 1;
    const int rr   = lane & 15, g4 = lane >> 4;

    f32x4 accg[4][4] = {};
    f32x4 accu[4][4] = {};

    const ushort_t* srcA0 = XP + (long)(mblk * 64) * 8192;
    const ushort_t* srcG0 = WP + (long)(nblk * 64) * 2 * 8192;

    for (int kt = 0; kt < KT1; ++kt) {
        __syncthreads();
        const ushort_t* sA = srcA0 + (long)kt * 8192;
        const ushort_t* sG = srcG0 + (long)kt * 2 * 8192;
#pragma unroll
        for (int j = 0; j < 12; ++j) {
            int q = j * 4 + w;          // 0..47; seg = j>>2 (compile-time)
            const ushort_t* s = (j < 4) ? sA : (j < 8) ? sG : (sG + 8192);
            gl_lds16(s + ((q & 15) << 9) + lane * 8, &lds[q << 9]);
        }
        __syncthreads();
#pragma unroll
        for (int ks = 0; ks < 2; ++ks) {
            const int c = ks * 4 + g4;
            bf16x8 a[4], bg[4], bu[4];
#pragma unroll
            for (int mf = 0; mf < 4; ++mf) {
                int r = wm * 64 + mf * 16 + rr;
                a[mf] = *(const bf16x8*)&lds[r * 64 + ((c ^ (r & 7)) << 3)];
            }
#pragma unroll
            for (int nf = 0; nf < 4; ++nf) {
                int r = wn * 64 + nf * 16 + rr;
                int off = r * 64 + ((c ^ (r & 7)) << 3);
                bg[nf] = *(const bf16x8*)&lds[8192 + off];
                bu[nf] = *(const bf16x8*)&lds[16384 + off];
            }
#pragma unroll
            for (int mf = 0; mf < 4; ++mf)
#pragma unroll
                for (int nf = 0; nf < 4; ++nf) {
                    accg[mf][nf] = __builtin_amdgcn_mfma_f32_16x16x32_bf16(a[mf], bg[nf], accg[mf][nf], 0, 0, 0);
                    accu[mf][nf] = __builtin_amdgcn_mfma_f32_16x16x32_bf16(a[mf], bu[nf], accu[mf][nf], 0, 0, 0);
                }
        }
    }
    // epilogue: silu(g)*u -> HP packed [mblk][kt2][128][64] with swizzle
#pragma unroll
    for (int nf = 0; nf < 4; ++nf) {
        int nloc = wn * 64 + nf * 16 + rr;
        int kt2  = nblk * 2 + (nloc >> 6);
        int kk   = nloc & 63;
        ushort_t* tp = HP + (long)(mblk * KT2 + kt2) * 8192;
        int obase = ((kk >> 3) << 3) + (kk & 7);   // chunk part before XOR, in ushorts
#pragma unroll
        for (int mf = 0; mf < 4; ++mf)
#pragma unroll
            for (int i = 0; i < 4; ++i) {
                int r = wm * 64 + mf * 16 + g4 * 4 + i;
                float gv = accg[mf][nf][i];
                float uv = accu[mf][nf][i];
                float s  = gv / (1.0f + __expf(-gv));
                int off = r * 64 + ((((kk >> 3) ^ (r & 7)) << 3)) + (kk & 7);
                tp[off] = (ushort_t)bf16rne(s * uv);
            }
        (void)obase;
    }
}

// ---------------- GEMM2: down projection ----------------
__global__ __launch_bounds__(256, 3)
void down2_kernel(const ushort_t* __restrict__ HP, const ushort_t* __restrict__ WP,
                  float* __restrict__ Out) {
    __shared__ ushort_t lds[16384];     // As(8192) | Bs(8192)

    int nwg = gridDim.x;                // 512
    int cpx = nwg >> 3;
    int sw  = (blockIdx.x & 7) * cpx + (blockIdx.x >> 3);
    int mblk = sw & 15;
    int nblk = sw >> 4;                 // 0..31

    const int t    = threadIdx.x;
    const int lane = t & 63;
    const int w    = t >> 6;
    const int wm   = w >> 1, wn = w & 1;
    const int rr   = lane & 15, g4 = lane >> 4;

    f32x4 acc[4][4] = {};

    const ushort_t* srcA0 = HP + (long)(mblk * KT2) * 8192;
    const ushort_t* srcB0 = WP + (long)(nblk * KT2) * 8192;

    for (int kt = 0; kt < KT2; ++kt) {
        __syncthreads();
        const ushort_t* sA = srcA0 + (long)kt * 8192;
        const ushort_t* sB = srcB0 + (long)kt * 8192;
#pragma unroll
        for (int j = 0; j < 8; ++j) {
            int q = j * 4 + w;          // 0..31
            const ushort_t* s = (j < 4) ? sA : sB;
            gl_lds16(s + ((q & 15) << 9) + lane * 8, &lds[q << 9]);
        }
        __syncthreads();
#pragma unroll
        for (int ks = 0; ks < 2; ++ks) {
            const int c = ks * 4 + g4;
            bf16x8 a[4], b[4];
#pragma unroll
            for (int mf = 0; mf < 4; ++mf) {
                int r = wm * 64 + mf * 16 + rr;
                a[mf] = *(const bf16x8*)&lds[r * 64 + ((c ^ (r & 7)) << 3)];
            }
#pragma unroll
            for (int nf = 0; nf < 4; ++nf) {
                int r = wn * 64 + nf * 16 + rr;
                b[nf] = *(const bf16x8*)&lds[8192 + r * 64 + ((c ^ (r & 7)) << 3)];
            }
#pragma unroll
            for (int mf = 0; mf < 4; ++mf)
#pragma unroll
                for (int nf = 0; nf < 4; ++nf)
                    acc[mf][nf] = __builtin_amdgcn_mfma_f32_16x16x32_bf16(a[mf], b[nf], acc[mf][nf], 0, 0, 0);
        }
    }
#pragma unroll
    for (int mf = 0; mf < 4; ++mf)
#pragma unroll
        for (int nf = 0; nf < 4; ++nf)
#pragma unroll
            for (int i = 0; i < 4; ++i) {
                int m = mblk * 128 + wm * 64 + mf * 16 + g4 * 4 + i;
                int n = nblk * 128 + wn * 64 + nf * 16 + rr;
                Out[(long)m * HDIM + n] = acc[mf][nf][i];
            }
}

// ================= round-1 fallback (fp32-read, convert-in-GEMM) =================
__device__ __forceinline__ int swz(int r) { return ((r >> 2) + ((r & 3) << 1)) & 7; }

__global__ __launch_bounds__(256, 2)
void gu_kernel(const float* __restrict__ X, const float* __restrict__ W,
               ushort_t* __restrict__ Hbuf) {
    __shared__ short As[BM * BK];
    __shared__ short Bg[BN * BK];
    __shared__ short Bu[BN * BK];
    int nwg = gridDim.x;
    int cpx = nwg >> 3;
    int sw  = (blockIdx.x & 7) * cpx + (blockIdx.x >> 3);
    int mblk = sw & 15, nblk = sw >> 4;
    const int m0 = mblk * BM, n0 = nblk * BN;
    const int t = threadIdx.x, lane = t & 63, w = t >> 6;
    const int wm = w >> 1, wn = w & 1, rr = lane & 15, g4 = lane >> 4;
    const int nc = t & 31, kc = t >> 5;
    f32x4 accg[4][4] = {}, accu[4][4] = {};
    for (int k0 = 0; k0 < HDIM; k0 += BK) {
        __syncthreads();
#pragma unroll
        for (int i = 0; i < 8; ++i) {
            int idx = t + i * 256, m = idx >> 4, c4 = idx & 15;
            f32x4 v = *(const f32x4*)(X + (long)(m0 + m) * HDIM + k0 + c4 * 4);
            u32x2 pk = { pack2(v[0], v[1]), pack2(v[2], v[3]) };
            *(u32x2*)&As[(m << 6) + ((((c4 >> 1) + swz(m)) & 7) << 3) + ((c4 & 1) << 2)] = pk;
        }
#pragma unroll
        for (int e = 0; e < 2; ++e) {
            const float* Wp = W + (long)(k0 + kc * 8) * N2 + (e ? (IDIM + n0) : n0) + nc * 4;
            short* Bl = e ? Bu : Bg;
#pragma unroll
            for (int h = 0; h < 2; ++h) {
                f32x4 r0 = *(const f32x4*)(Wp + (long)(h * 4 + 0) * N2);
                f32x4 r1 = *(const f32x4*)(Wp + (long)(h * 4 + 1) * N2);
                f32x4 r2 = *(const f32x4*)(Wp + (long)(h * 4 + 2) * N2);
                f32x4 r3 = *(const f32x4*)(Wp + (long)(h * 4 + 3) * N2);
#pragma unroll
                for (int c2 = 0; c2 < 4; ++c2) {
                    int n = nc * 4 + c2;
                    u32x2 pk = { pack2(r0[c2], r1[c2]), pack2(r2[c2], r3[c2]) };
                    *(u32x2*)&Bl[(n << 6) + (((kc + swz(n)) & 7) << 3) + (h << 2)] = pk;
                }
            }
        }
        __syncthreads();
#pragma unroll
        for (int ks = 0; ks < 2; ++ks) {
            bf16x8 a[4], bg[4], bu[4];
#pragma unroll
            for (int mf = 0; mf < 4; ++mf) {
                int r = wm * 64 + mf * 16 + rr;
                a[mf] = *(const bf16x8*)&As[(r << 6) + ((((ks * 4 + g4) + swz(r)) & 7) << 3)];
            }
#pragma unroll
            for (int nf = 0; nf < 4; ++nf) {
                int r = wn * 64 + nf * 16 + rr;
                int off = (r << 6) + ((((ks * 4 + g4) + swz(r)) & 7) << 3);
                bg[nf] = *(const bf16x8*)&Bg[off];
                bu[nf] = *(const bf16x8*)&Bu[off];
            }
#pragma unroll
            for (int mf = 0; mf < 4; ++mf)
#pragma unroll
                for (int nf = 0; nf < 4; ++nf) {
                    accg[mf][nf] = __builtin_amdgcn_mfma_f32_16x16x32_bf16(a[mf], bg[nf], accg[mf][nf], 0, 0, 0);
                    accu[mf][nf] = __builtin_amdgcn_mfma_f32_16x16x32_bf16(a[mf], bu[nf], accu[mf][nf], 0, 0, 0);
                }
        }
    }
#pragma unroll
    for (int mf = 0; mf < 4; ++mf)
#pragma unroll
        for (int nf = 0; nf < 4; ++nf)
#pragma unroll
            for (int i = 0; i < 4; ++i) {
                int m = m0 + wm * 64 + mf * 16 + g4 * 4 + i;
                int n = n0 + wn * 64 + nf * 16 + rr;
                float gv = accg[mf][nf][i], uv = accu[mf][nf][i];
                Hbuf[(long)m * IDIM + n] = (ushort_t)bf16rne(gv / (1.0f + __expf(-gv)) * uv);
            }
}

__global__ __launch_bounds__(256, 2)
void down_kernel(const ushort_t* __restrict__ Hbuf, const float* __restrict__ W,
                 float* __restrict__ Out) {
    __shared__ short As[BM * BK];
    __shared__ short Bs[BN * BK];
    int nwg = gridDim.x;
    int cpx = nwg >> 3;
    int sw  = (blockIdx.x & 7) * cpx + (blockIdx.x >> 3);
    int mblk = sw & 15, nblk = sw >> 4;
    const int m0 = mblk * BM, n0 = nblk * BN;
    const int t = threadIdx.x, lane = t & 63, w = t >> 6;
    const int wm = w >> 1, wn = w & 1, rr = lane & 15, g4 = lane >> 4;
    const int nc = t & 31, kc = t >> 5;
    f32x4 acc[4][4] = {};
    for (int k0 = 0; k0 < IDIM; k0 += BK) {
        __syncthreads();
#pragma unroll
        for (int i = 0; i < 4; ++i) {
            int idx = t + i * 256, m = idx >> 3, kc8 = idx & 7;
            u32x4 v = *(const u32x4*)(Hbuf + (long)(m0 + m) * IDIM + k0 + kc8 * 8);
            *(u32x4*)&As[(m << 6) + (((kc8 + swz(m)) & 7) << 3)] = v;
        }
        {
            const float* Wp = W + (long)(k0 + kc * 8) * HDIM + n0 + nc * 4;
#pragma unroll
            for (int h = 0; h < 2; ++h) {
                f32x4 r0 = *(const f32x4*)(Wp + (long)(h * 4 + 0) * HDIM);
                f32x4 r1 = *(const f32x4*)(Wp + (long)(h * 4 + 1) * HDIM);
                f32x4 r2 = *(const f32x4*)(Wp + (long)(h * 4 + 2) * HDIM);
                f32x4 r3 = *(const f32x4*)(Wp + (long)(h * 4 + 3) * HDIM);
#pragma unroll
                for (int c2 = 0; c2 < 4; ++c2) {
                    int n = nc * 4 + c2;
                    u32x2 pk = { pack2(r0[c2], r1[c2]), pack2(r2[c2], r3[c2]) };
                    *(u32x2*)&Bs[(n << 6) + (((kc + swz(n)) & 7) << 3) + (h << 2)] = pk;
                }
            }
        }
        __syncthreads();
#pragma unroll
        for (int ks = 0; ks < 2; ++ks) {
            bf16x8 a[4], b[4];
#pragma unroll
            for (int mf = 0; mf < 4; ++mf) {
                int r = wm * 64 + mf * 16 + rr;
                a[mf] = *(const bf16x8*)&As[(r << 6) + ((((ks * 4 + g4) + swz(r)) & 7) << 3)];
            }
#pragma unroll
            for (int nf = 0; nf < 4; ++nf) {
                int r = wn * 64 + nf * 16 + rr;
                b[nf] = *(const bf16x8*)&Bs[(r << 6) + ((((ks * 4 + g4) + swz(r)) & 7) << 3)];
            }
#pragma unroll
            for (int mf = 0; mf < 4; ++mf)
#pragma unroll
                for (int nf = 0; nf < 4; ++nf)
                    acc[mf][nf] = __builtin_amdgcn_mfma_f32_16x16x32_bf16(a[mf], b[nf], acc[mf][nf], 0, 0, 0);
        }
    }
#pragma unroll
    for (int mf = 0; mf < 4; ++mf)
#pragma unroll
        for (int nf = 0; nf < 4; ++nf)
#pragma unroll
            for (int i = 0; i < 4; ++i) {
                int m = m0 + wm * 64 + mf * 16 + g4 * 4 + i;
                int n = n0 + wn * 64 + nf * 16 + rr;
                Out[(long)m * HDIM + n] = acc[mf][nf][i];
            }
}

// ================= host =================
extern "C" void kernel_launch(void* const* d_in, const int* in_sizes, int n_in,
                              void* d_out, int out_size, void* d_ws, size_t ws_size,
                              hipStream_t stream) {
    const float* x     = (const float*)d_in[0];
    const float* Wgu_l = (const float*)d_in[3];
    const float* Wd_l  = (const float*)d_in[4];
    const float* Wgu_v = (const float*)d_in[5];
    const float* Wd_v  = (const float*)d_in[6];
    float* out         = (float*)d_out;

    const size_t XP_B = (size_t)16 * KT1 * 16384;        //  16.8 MB
    const size_t HP_B = (size_t)16 * KT2 * 16384;        //  45.1 MB
    const size_t WP_B = (size_t)NB1 * KT1 * 2 * 16384;   // 180.4 MB
    const size_t NEED = XP_B + HP_B + WP_B;              // 242.2 MB

    if (ws_size >= NEED) {
        ushort_t* XP = (ushort_t*)d_ws;
        ushort_t* HP = XP + XP_B / 2;
        ushort_t* WP = HP + HP_B / 2;
        for (int e = 0; e < 2; ++e) {
            const float* xe = x + (long)e * MTOK * HDIM;
            float*       oe = out + (long)e * MTOK * HDIM;
            conv_x  <<<dim3(16 * KT1),      dim3(256), 0, stream>>>(xe, XP);
            conv_wgu<<<dim3(NB1 * KT1 * 2), dim3(256), 0, stream>>>(e ? Wgu_v : Wgu_l, WP);
            gu2_kernel<<<dim3(16 * NB1),    dim3(256), 0, stream>>>(XP, WP, HP);
            conv_wd <<<dim3(NB2 * KT2),     dim3(256), 0, stream>>>(e ? Wd_v : Wd_l, WP);
            down2_kernel<<<dim3(16 * NB2),  dim3(256), 0, stream>>>(HP, WP, oe);
        }
    } else {
        ushort_t* hbuf = (ushort_t*)d_ws;   // 45.1 MB
        for (int e = 0; e < 2; ++e) {
            const float* Wgu = e ? Wgu_v : Wgu_l;
            const float* Wd  = e ? Wd_v  : Wd_l;
            const float* xe  = x   + (long)e * MTOK * HDIM;
            float*       oe  = out + (long)e * MTOK * HDIM;
            gu_kernel  <<<dim3(16 * NB1), dim3(256), 0, stream>>>(xe, Wgu, hbuf);
            down_kernel<<<dim3(16 * NB2), dim3(256), 0, stream>>>(hbuf, Wd, oe);
        }
    }
}

// Round 4
// 1308.111 us; speedup vs baseline: 2.1708x; 1.1226x over previous
//
#include <hip/hip_runtime.h>
#include <hip/hip_bf16.h>

// Round 4: round-3 8-phase counted-vmcnt GEMMs + TAIL FIX.
// Bug in round 3: last K-iteration issues no prefetch (pf=false), so the
// steady-state vmcnt(4)/vmcnt(2) waits became no-ops and the last tile's
// second half could be read before its global_load_lds landed (rare stale
// reads -> absmax 0.195). Fix: drain the ledger in the tail:
//   mid-tile wait:  vmcnt(pf ? 4 : 0)
//   end-tile wait:  only when pf (nothing left to cover afterwards).
//
// Pack layout, tile = [R rows][64 k] bf16, stored k-half-contiguous:
//   [kh = k>>5][q = r>>1][pos][klow = k&7] shorts, pos = (((r&1)<<2)|((k>>3)&3)) ^ (q&7)
// Staging: global_load_lds width-16, linear LDS dest (swizzle pre-baked in pack).

#define HDIM 4096
#define IDIM 11008
#define N2   22016
#define MTOK 2048
#define BM   128
#define BN   128
#define BK   64
#define KT1  64      // HDIM/64
#define KT2  172     // IDIM/64
#define NB1  86      // IDIM/128
#define NB2  32      // HDIM/128

typedef unsigned short ushort_t;
using f32x4  = __attribute__((ext_vector_type(4))) float;
using bf16x8 = __attribute__((ext_vector_type(8))) short;
using u32x2  = __attribute__((ext_vector_type(2))) unsigned int;
using u32x4  = __attribute__((ext_vector_type(4))) unsigned int;

__device__ __forceinline__ unsigned int bf16rne(float f) {
    unsigned int u = __builtin_bit_cast(unsigned int, f);
    return (u + 0x7FFFu + ((u >> 16) & 1u)) >> 16;
}
__device__ __forceinline__ unsigned int pack2(float lo, float hi) {
    return bf16rne(lo) | (bf16rne(hi) << 16);
}
__device__ __forceinline__ void gl_lds16(const void* g, void* l) {
    __builtin_amdgcn_global_load_lds(
        (const __attribute__((address_space(1))) void*)g,
        (__attribute__((address_space(3))) void*)l, 16, 0, 0);
}

// ---------------- conversion kernels (fp32 -> packed bf16) ----------------

// x [2048][4096] -> XP [mb256(8)][kt(64)] 32KB tiles
__global__ __launch_bounds__(256)
void conv_x(const float* __restrict__ X, ushort_t* __restrict__ XP) {
    int bid = blockIdx.x;               // 16 mb128 * 64 kt
    int mb = bid >> 6, kt = bid & 63;
    int t = threadIdx.x;
    int r0 = t >> 4, c4 = t & 15;
    int kh = c4 >> 3, c = (c4 >> 1) & 3, lo4 = (c4 & 1) << 2;
    ushort_t* tp = XP + ((long)(mb >> 1) * KT1 + kt) * 16384 + (long)kh * 8192 + (mb & 1) * 4096;
#pragma unroll
    for (int p = 0; p < 8; ++p) {
        int rl = r0 + p * 16;
        f32x4 v = *(const f32x4*)(X + (long)(mb * 128 + rl) * HDIM + kt * 64 + c4 * 4);
        u32x2 pk = { pack2(v[0], v[1]), pack2(v[2], v[3]) };
        int q = rl >> 1;
        int pos = ((((rl & 1) << 2) | c) ^ (q & 7));
        *(u32x2*)&tp[q * 64 + pos * 8 + lo4] = pk;
    }
}

// Wgu [4096][22016] -> WP [(nb*64+kt)] 32KB tiles: [kh][g 4KB | u 4KB]
__global__ __launch_bounds__(256)
void conv_wgu(const float* __restrict__ W, ushort_t* __restrict__ WP) {
    int bid = blockIdx.x;               // nb(86)*kt(64)*e(2)
    int e = bid & 1, kt = (bid >> 1) & 63, nb = bid >> 7;
    int t = threadIdx.x;
    int kp = t >> 5, c4 = t & 31;
    const float* p = W + ((long)kt * 64 + kp * 8) * N2 + (long)e * IDIM + nb * 128 + c4 * 4;
    f32x4 v[8];
#pragma unroll
    for (int j = 0; j < 8; ++j) v[j] = *(const f32x4*)(p + (long)j * N2);
    ushort_t* tp = WP + ((long)nb * KT1 + kt) * 16384 + (long)(kp >> 2) * 8192 + e * 4096;
    int c = kp & 3;
#pragma unroll
    for (int cc = 0; cc < 4; ++cc) {
        int n = c4 * 4 + cc;
        int q = n >> 1;
        int pos = ((((n & 1) << 2) | c) ^ (q & 7));
        u32x4 pk = { pack2(v[0][cc], v[1][cc]), pack2(v[2][cc], v[3][cc]),
                     pack2(v[4][cc], v[5][cc]), pack2(v[6][cc], v[7][cc]) };
        *(u32x4*)&tp[q * 64 + pos * 8] = pk;
    }
}

// Wd [11008][4096] -> WP [(nb*172+kt)] 16KB tiles: [kh 8KB][kh 8KB]
__global__ __launch_bounds__(256)
void conv_wd(const float* __restrict__ W, ushort_t* __restrict__ WP) {
    int bid = blockIdx.x;               // nb(32)*kt(172)
    int kt = bid % KT2, nb = bid / KT2;
    int t = threadIdx.x;
    int kp = t >> 5, c4 = t & 31;
    const float* p = W + ((long)kt * 64 + kp * 8) * HDIM + nb * 128 + c4 * 4;
    f32x4 v[8];
#pragma unroll
    for (int j = 0; j < 8; ++j) v[j] = *(const f32x4*)(p + (long)j * HDIM);
    ushort_t* tp = WP + ((long)nb * KT2 + kt) * 8192 + (long)(kp >> 2) * 4096;
    int c = kp & 3;
#pragma unroll
    for (int cc = 0; cc < 4; ++cc) {
        int n = c4 * 4 + cc;
        int q = n >> 1;
        int pos = ((((n & 1) << 2) | c) ^ (q & 7));
        u32x4 pk = { pack2(v[0][cc], v[1][cc]), pack2(v[2][cc], v[3][cc]),
                     pack2(v[4][cc], v[5][cc]), pack2(v[6][cc], v[7][cc]) };
        *(u32x4*)&tp[q * 64 + pos * 8] = pk;
    }
}

// stage one 16KB unit (8192 shorts): 2 x global_load_lds per thread, linear dest
#define STAGE_U(SRC, DSTOFF) do { \
    gl_lds16((SRC) + so + lane * 8, &lds[(DSTOFF) + so]); \
    gl_lds16((SRC) + 4096 + so + lane * 8, &lds[(DSTOFF) + 4096 + so]); } while (0)

#define MFMA16(ACC, AF, BF) \
    _Pragma("unroll") \
    for (int mf = 0; mf < 4; ++mf) \
        _Pragma("unroll") \
        for (int nf = 0; nf < 4; ++nf) \
            ACC[mf][nf] = __builtin_amdgcn_mfma_f32_16x16x32_bf16(AF[mf], BF[nf], ACC[mf][nf], 0, 0, 0);

#define VMCNT_MID(N) do { \
    if (pf) asm volatile("s_waitcnt vmcnt(" #N ")" ::: "memory"); \
    else    asm volatile("s_waitcnt vmcnt(0)" ::: "memory"); } while (0)
#define VMCNT_END(N) do { \
    if (pf) asm volatile("s_waitcnt vmcnt(" #N ")" ::: "memory"); } while (0)

// ---------------- GEMM1: 8-phase fused gate/up + silu ----------------
__global__ __launch_bounds__(512, 2)
void gu3_kernel(const ushort_t* __restrict__ XP, const ushort_t* __restrict__ WP,
                ushort_t* __restrict__ HP) {
    __shared__ ushort_t lds[65536];     // [2 buf][U0 A-k0 | U1 Bg|Bu-k0 | U2 A-k1 | U3 Bg|Bu-k1]
    int nwg = gridDim.x;                // 688
    int cpx = nwg >> 3;
    int sw  = (blockIdx.x & 7) * cpx + (blockIdx.x >> 3);
    int mblk = sw & 7;                  // 0..7
    int nblk = sw >> 3;                 // 0..85
    const int t = threadIdx.x, lane = t & 63, w = t >> 6;
    const int wr = w >> 1, wc = w & 1;  // 4M x 2N waves
    const int rr = lane & 15, g4 = lane >> 4;
    const int so = w * 512;

    int aoff[4], boff[4];
#pragma unroll
    for (int mf = 0; mf < 4; ++mf) {
        int m = wr * 64 + mf * 16 + rr, q = m >> 1;
        aoff[mf] = q * 64 + ((((((m & 1) << 2) | g4) ^ (q & 7))) << 3);
    }
#pragma unroll
    for (int nf = 0; nf < 4; ++nf) {
        int n = wc * 64 + nf * 16 + rr, q = n >> 1;
        boff[nf] = q * 64 + ((((((n & 1) << 2) | g4) ^ (q & 7))) << 3);
    }

    f32x4 accg[4][4] = {}, accu[4][4] = {};
    const ushort_t* srcA = XP + (long)mblk * KT1 * 16384;
    const ushort_t* srcB = WP + (long)nblk * KT1 * 16384;

    // prologue: full tile 0 into buf0
    STAGE_U(srcA, 0);
    STAGE_U(srcB, 8192);
    STAGE_U(srcA + 8192, 16384);
    STAGE_U(srcB + 8192, 24576);
    asm volatile("s_waitcnt vmcnt(0)" ::: "memory");
    __builtin_amdgcn_s_barrier();

    int cur = 0;
    for (int kt = 0; kt < KT1; ++kt) {
        const int cb = cur * 32768, pb = (cur ^ 1) * 32768;
        const ushort_t* nA = srcA + (long)(kt + 1) * 16384;
        const ushort_t* nB = srcB + (long)(kt + 1) * 16384;
        const bool pf = (kt + 1 < KT1);
        bf16x8 af[4], bfr[4];

        // ---- p0: ks0 gate ----
#pragma unroll
        for (int mf = 0; mf < 4; ++mf) af[mf] = *(const bf16x8*)&lds[cb + aoff[mf]];
#pragma unroll
        for (int nf = 0; nf < 4; ++nf) bfr[nf] = *(const bf16x8*)&lds[cb + 8192 + boff[nf]];
        if (pf) STAGE_U(nA, pb);
        __builtin_amdgcn_s_barrier();
        __builtin_amdgcn_s_setprio(1);
        MFMA16(accg, af, bfr);
        __builtin_amdgcn_s_setprio(0);
        __builtin_amdgcn_s_barrier();

        // ---- p1: ks0 up ----
#pragma unroll
        for (int nf = 0; nf < 4; ++nf) bfr[nf] = *(const bf16x8*)&lds[cb + 12288 + boff[nf]];
        if (pf) STAGE_U(nB, pb + 8192);
        __builtin_amdgcn_s_barrier();
        __builtin_amdgcn_s_setprio(1);
        MFMA16(accu, af, bfr);
        __builtin_amdgcn_s_setprio(0);
        VMCNT_MID(4);                       // lands U2,U3(cur tile); full drain on tail
        __builtin_amdgcn_s_barrier();

        // ---- p2: ks1 gate ----
#pragma unroll
        for (int mf = 0; mf < 4; ++mf) af[mf] = *(const bf16x8*)&lds[cb + 16384 + aoff[mf]];
#pragma unroll
        for (int nf = 0; nf < 4; ++nf) bfr[nf] = *(const bf16x8*)&lds[cb + 24576 + boff[nf]];
        if (pf) STAGE_U(nA + 8192, pb + 16384);
        __builtin_amdgcn_s_barrier();
        __builtin_amdgcn_s_setprio(1);
        MFMA16(accg, af, bfr);
        __builtin_amdgcn_s_setprio(0);
        __builtin_amdgcn_s_barrier();

        // ---- p3: ks1 up ----
#pragma unroll
        for (int nf = 0; nf < 4; ++nf) bfr[nf] = *(const bf16x8*)&lds[cb + 28672 + boff[nf]];
        if (pf) STAGE_U(nB + 8192, pb + 24576);
        __builtin_amdgcn_s_barrier();
        __builtin_amdgcn_s_setprio(1);
        MFMA16(accu, af, bfr);
        __builtin_amdgcn_s_setprio(0);
        VMCNT_END(4);                       // lands U0,U1(next tile); skip on tail
        __builtin_amdgcn_s_barrier();

        cur ^= 1;
    }

    // epilogue: silu(g)*u -> HP packed tiles
#pragma unroll
    for (int nf = 0; nf < 4; ++nf) {
        int nloc = wc * 64 + nf * 16 + rr;
        int kt2 = nblk * 2 + (nloc >> 6);
        int k = nloc & 63;
        int kh = k >> 5, c = (k >> 3) & 3, klow = k & 7;
        ushort_t* tp = HP + ((long)mblk * KT2 + kt2) * 16384 + kh * 8192 + klow;
#pragma unroll
        for (int mf = 0; mf < 4; ++mf)
#pragma unroll
            for (int i = 0; i < 4; ++i) {
                int m = wr * 64 + mf * 16 + g4 * 4 + i;
                int q = m >> 1;
                int pos = ((((m & 1) << 2) | c) ^ (q & 7));
                float gv = accg[mf][nf][i], uv = accu[mf][nf][i];
                float s = gv / (1.0f + __expf(-gv));
                tp[q * 64 + pos * 8] = (ushort_t)bf16rne(s * uv);
            }
    }
}

// ---------------- GEMM2: 2-phase-per-K-tile down projection ----------------
__global__ __launch_bounds__(512, 2)
void down3_kernel(const ushort_t* __restrict__ HP, const ushort_t* __restrict__ WP,
                  float* __restrict__ Out) {
    __shared__ ushort_t lds[49152];     // [2 buf][A-k0 | A-k1 | B(kh0|kh1)]
    int nwg = gridDim.x;                // 256
    int cpx = nwg >> 3;
    int sw  = (blockIdx.x & 7) * cpx + (blockIdx.x >> 3);
    int mblk = sw & 7;                  // 0..7
    int nblk = sw >> 3;                 // 0..31
    const int t = threadIdx.x, lane = t & 63, w = t >> 6;
    const int wr = w >> 1, wc = w & 1;
    const int rr = lane & 15, g4 = lane >> 4;
    const int so = w * 512;

    int aoff[4], boff[4];
#pragma unroll
    for (int mf = 0; mf < 4; ++mf) {
        int m = wr * 64 + mf * 16 + rr, q = m >> 1;
        aoff[mf] = q * 64 + ((((((m & 1) << 2) | g4) ^ (q & 7))) << 3);
    }
#pragma unroll
    for (int nf = 0; nf < 4; ++nf) {
        int n = wc * 64 + nf * 16 + rr, q = n >> 1;
        boff[nf] = q * 64 + ((((((n & 1) << 2) | g4) ^ (q & 7))) << 3);
    }

    f32x4 acc[4][4] = {};
    const ushort_t* srcA = HP + (long)mblk * KT2 * 16384;
    const ushort_t* srcB = WP + (long)nblk * KT2 * 8192;

    STAGE_U(srcA, 0);
    STAGE_U(srcA + 8192, 8192);
    STAGE_U(srcB, 16384);
    asm volatile("s_waitcnt vmcnt(0)" ::: "memory");
    __builtin_amdgcn_s_barrier();

    int cur = 0;
    for (int kt = 0; kt < KT2; ++kt) {
        const int cb = cur * 24576, pb = (cur ^ 1) * 24576;
        const ushort_t* nA = srcA + (long)(kt + 1) * 16384;
        const ushort_t* nB = srcB + (long)(kt + 1) * 8192;
        const bool pf = (kt + 1 < KT2);
        bf16x8 af[4], bfr[4];

        // ---- p0: ks0 ----
#pragma unroll
        for (int mf = 0; mf < 4; ++mf) af[mf] = *(const bf16x8*)&lds[cb + aoff[mf]];
#pragma unroll
        for (int nf = 0; nf < 4; ++nf) bfr[nf] = *(const bf16x8*)&lds[cb + 16384 + boff[nf]];
        if (pf) { STAGE_U(nA, pb); STAGE_U(nB, pb + 16384); }
        __builtin_amdgcn_s_barrier();
        __builtin_amdgcn_s_setprio(1);
        MFMA16(acc, af, bfr);
        __builtin_amdgcn_s_setprio(0);
        VMCNT_MID(4);                       // lands A-k1(cur tile); full drain on tail
        __builtin_amdgcn_s_barrier();

        // ---- p1: ks1 ----
#pragma unroll
        for (int mf = 0; mf < 4; ++mf) af[mf] = *(const bf16x8*)&lds[cb + 8192 + aoff[mf]];
#pragma unroll
        for (int nf = 0; nf < 4; ++nf) bfr[nf] = *(const bf16x8*)&lds[cb + 20480 + boff[nf]];
        if (pf) STAGE_U(nA + 8192, pb + 8192);
        __builtin_amdgcn_s_barrier();
        __builtin_amdgcn_s_setprio(1);
        MFMA16(acc, af, bfr);
        __builtin_amdgcn_s_setprio(0);
        VMCNT_END(2);                       // lands A-k0,B(next tile); skip on tail
        __builtin_amdgcn_s_barrier();

        cur ^= 1;
    }

#pragma unroll
    for (int mf = 0; mf < 4; ++mf)
#pragma unroll
        for (int nf = 0; nf < 4; ++nf)
#pragma unroll
            for (int i = 0; i < 4; ++i) {
                int m = mblk * 256 + wr * 64 + mf * 16 + g4 * 4 + i;
                int n = nblk * 128 + wc * 64 + nf * 16 + rr;
                Out[(long)m * HDIM + n] = acc[mf][nf][i];
            }
}

// ================= round-1 fallback (fp32-read, convert-in-GEMM) =================
__device__ __forceinline__ int swz(int r) { return ((r >> 2) + ((r & 3) << 1)) & 7; }

__global__ __launch_bounds__(256, 2)
void gu_kernel(const float* __restrict__ X, const float* __restrict__ W,
               ushort_t* __restrict__ Hbuf) {
    __shared__ short As[BM * BK];
    __shared__ short Bg[BN * BK];
    __shared__ short Bu[BN * BK];
    int nwg = gridDim.x;
    int cpx = nwg >> 3;
    int sw  = (blockIdx.x & 7) * cpx + (blockIdx.x >> 3);
    int mblk = sw & 15, nblk = sw >> 4;
    const int m0 = mblk * BM, n0 = nblk * BN;
    const int t = threadIdx.x, lane = t & 63, w = t >> 6;
    const int wm = w >> 1, wn = w & 1, rr = lane & 15, g4 = lane >> 4;
    const int nc = t & 31, kc = t >> 5;
    f32x4 accg[4][4] = {}, accu[4][4] = {};
    for (int k0 = 0; k0 < HDIM; k0 += BK) {
        __syncthreads();
#pragma unroll
        for (int i = 0; i < 8; ++i) {
            int idx = t + i * 256, m = idx >> 4, c4 = idx & 15;
            f32x4 v = *(const f32x4*)(X + (long)(m0 + m) * HDIM + k0 + c4 * 4);
            u32x2 pk = { pack2(v[0], v[1]), pack2(v[2], v[3]) };
            *(u32x2*)&As[(m << 6) + ((((c4 >> 1) + swz(m)) & 7) << 3) + ((c4 & 1) << 2)] = pk;
        }
#pragma unroll
        for (int e = 0; e < 2; ++e) {
            const float* Wp = W + (long)(k0 + kc * 8) * N2 + (e ? (IDIM + n0) : n0) + nc * 4;
            short* Bl = e ? Bu : Bg;
#pragma unroll
            for (int h = 0; h < 2; ++h) {
                f32x4 r0 = *(const f32x4*)(Wp + (long)(h * 4 + 0) * N2);
                f32x4 r1 = *(const f32x4*)(Wp + (long)(h * 4 + 1) * N2);
                f32x4 r2 = *(const f32x4*)(Wp + (long)(h * 4 + 2) * N2);
                f32x4 r3 = *(const f32x4*)(Wp + (long)(h * 4 + 3) * N2);
#pragma unroll
                for (int c2 = 0; c2 < 4; ++c2) {
                    int n = nc * 4 + c2;
                    u32x2 pk = { pack2(r0[c2], r1[c2]), pack2(r2[c2], r3[c2]) };
                    *(u32x2*)&Bl[(n << 6) + (((kc + swz(n)) & 7) << 3) + (h << 2)] = pk;
                }
            }
        }
        __syncthreads();
#pragma unroll
        for (int ks = 0; ks < 2; ++ks) {
            bf16x8 a[4], bg[4], bu[4];
#pragma unroll
            for (int mf = 0; mf < 4; ++mf) {
                int r = wm * 64 + mf * 16 + rr;
                a[mf] = *(const bf16x8*)&As[(r << 6) + ((((ks * 4 + g4) + swz(r)) & 7) << 3)];
            }
#pragma unroll
            for (int nf = 0; nf < 4; ++nf) {
                int r = wn * 64 + nf * 16 + rr;
                int off = (r << 6) + ((((ks * 4 + g4) + swz(r)) & 7) << 3);
                bg[nf] = *(const bf16x8*)&Bg[off];
                bu[nf] = *(const bf16x8*)&Bu[off];
            }
#pragma unroll
            for (int mf = 0; mf < 4; ++mf)
#pragma unroll
                for (int nf = 0; nf < 4; ++nf) {
                    accg[mf][nf] = __builtin_amdgcn_mfma_f32_16x16x32_bf16(a[mf], bg[nf], accg[mf][nf], 0, 0, 0);
                    accu[mf][nf] = __builtin_amdgcn_mfma_f32_16x16x32_bf16(a[mf], bu[nf], accu[mf][nf], 0, 0, 0);
                }
        }
    }
#pragma unroll
    for (int mf = 0; mf < 4; ++mf)
#pragma unroll
        for (int nf = 0; nf < 4; ++nf)
#pragma unroll
            for (int i = 0; i < 4; ++i) {
                int m = m0 + wm * 64 + mf * 16 + g4 * 4 + i;
                int n = n0 + wn * 64 + nf * 16 + rr;
                float gv = accg[mf][nf][i], uv = accu[mf][nf][i];
                Hbuf[(long)m * IDIM + n] = (ushort_t)bf16rne(gv / (1.0f + __expf(-gv)) * uv);
            }
}

__global__ __launch_bounds__(256, 2)
void down_kernel(const ushort_t* __restrict__ Hbuf, const float* __restrict__ W,
                 float* __restrict__ Out) {
    __shared__ short As[BM * BK];
    __shared__ short Bs[BN * BK];
    int nwg = gridDim.x;
    int cpx = nwg >> 3;
    int sw  = (blockIdx.x & 7) * cpx + (blockIdx.x >> 3);
    int mblk = sw & 15, nblk = sw >> 4;
    const int m0 = mblk * BM, n0 = nblk * BN;
    const int t = threadIdx.x, lane = t & 63, w = t >> 6;
    const int wm = w >> 1, wn = w & 1, rr = lane & 15, g4 = lane >> 4;
    const int nc = t & 31, kc = t >> 5;
    f32x4 acc[4][4] = {};
    for (int k0 = 0; k0 < IDIM; k0 += BK) {
        __syncthreads();
#pragma unroll
        for (int i = 0; i < 4; ++i) {
            int idx = t + i * 256, m = idx >> 3, kc8 = idx & 7;
            u32x4 v = *(const u32x4*)(Hbuf + (long)(m0 + m) * IDIM + k0 + kc8 * 8);
            *(u32x4*)&As[(m << 6) + (((kc8 + swz(m)) & 7) << 3)] = v;
        }
        {
            const float* Wp = W + (long)(k0 + kc * 8) * HDIM + n0 + nc * 4;
#pragma unroll
            for (int h = 0; h < 2; ++h) {
                f32x4 r0 = *(const f32x4*)(Wp + (long)(h * 4 + 0) * HDIM);
                f32x4 r1 = *(const f32x4*)(Wp + (long)(h * 4 + 1) * HDIM);
                f32x4 r2 = *(const f32x4*)(Wp + (long)(h * 4 + 2) * HDIM);
                f32x4 r3 = *(const f32x4*)(Wp + (long)(h * 4 + 3) * HDIM);
#pragma unroll
                for (int c2 = 0; c2 < 4; ++c2) {
                    int n = nc * 4 + c2;
                    u32x2 pk = { pack2(r0[c2], r1[c2]), pack2(r2[c2], r3[c2]) };
                    *(u32x2*)&Bs[(n << 6) + (((kc + swz(n)) & 7) << 3) + (h << 2)] = pk;
                }
            }
        }
        __syncthreads();
#pragma unroll
        for (int ks = 0; ks < 2; ++ks) {
            bf16x8 a[4], b[4];
#pragma unroll
            for (int mf = 0; mf < 4; ++mf) {
                int r = wm * 64 + mf * 16 + rr;
                a[mf] = *(const bf16x8*)&As[(r << 6) + ((((ks * 4 + g4) + swz(r)) & 7) << 3)];
            }
#pragma unroll
            for (int nf = 0; nf < 4; ++nf) {
                int r = wn * 64 + nf * 16 + rr;
                b[nf] = *(const bf16x8*)&Bs[(r << 6) + ((((ks * 4 + g4) + swz(r)) & 7) << 3)];
            }
#pragma unroll
            for (int mf = 0; mf < 4; ++mf)
#pragma unroll
                for (int nf = 0; nf < 4; ++nf)
                    acc[mf][nf] = __builtin_amdgcn_mfma_f32_16x16x32_bf16(a[mf], b[nf], acc[mf][nf], 0, 0, 0);
        }
    }
#pragma unroll
    for (int mf = 0; mf < 4; ++mf)
#pragma unroll
        for (int nf = 0; nf < 4; ++nf)
#pragma unroll
            for (int i = 0; i < 4; ++i) {
                int m = m0 + wm * 64 + mf * 16 + g4 * 4 + i;
                int n = n0 + wn * 64 + nf * 16 + rr;
                Out[(long)m * HDIM + n] = acc[mf][nf][i];
            }
}

// ================= host =================
extern "C" void kernel_launch(void* const* d_in, const int* in_sizes, int n_in,
                              void* d_out, int out_size, void* d_ws, size_t ws_size,
                              hipStream_t stream) {
    const float* x     = (const float*)d_in[0];
    const float* Wgu_l = (const float*)d_in[3];
    const float* Wd_l  = (const float*)d_in[4];
    const float* Wgu_v = (const float*)d_in[5];
    const float* Wd_v  = (const float*)d_in[6];
    float* out         = (float*)d_out;

    const size_t XP_B = (size_t)8 * KT1 * 32768;         //  16.8 MB
    const size_t HP_B = (size_t)8 * KT2 * 32768;         //  45.1 MB
    const size_t WP_B = (size_t)NB1 * KT1 * 32768;       // 180.4 MB (Wd pack 90.2 MB reuses it)
    const size_t NEED = XP_B + HP_B + WP_B;              // 242.2 MB

    if (ws_size >= NEED) {
        ushort_t* XP = (ushort_t*)d_ws;
        ushort_t* HP = XP + XP_B / 2;
        ushort_t* WP = HP + HP_B / 2;
        for (int e = 0; e < 2; ++e) {
            const float* xe = x + (long)e * MTOK * HDIM;
            float*       oe = out + (long)e * MTOK * HDIM;
            conv_x  <<<dim3(16 * KT1),      dim3(256), 0, stream>>>(xe, XP);
            conv_wgu<<<dim3(NB1 * KT1 * 2), dim3(256), 0, stream>>>(e ? Wgu_v : Wgu_l, WP);
            gu3_kernel<<<dim3(8 * NB1),     dim3(512), 0, stream>>>(XP, WP, HP);
            conv_wd <<<dim3(NB2 * KT2),     dim3(256), 0, stream>>>(e ? Wd_v : Wd_l, WP);
            down3_kernel<<<dim3(8 * NB2),   dim3(512), 0, stream>>>(HP, WP, oe);
        }
    } else {
        ushort_t* hbuf = (ushort_t*)d_ws;   // 45.1 MB
        for (int e = 0; e < 2; ++e) {
            const float* Wgu = e ? Wgu_v : Wgu_l;
            const float* Wd  = e ? Wd_v  : Wd_l;
            const float* xe  = x   + (long)e * MTOK * HDIM;
            float*       oe  = out + (long)e * MTOK * HDIM;
            gu_kernel  <<<dim3(16 * NB1), dim3(256), 0, stream>>>(xe, Wgu, hbuf);
            down_kernel<<<dim3(16 * NB2), dim3(256), 0, stream>>>(hbuf, Wd, oe);
        }
    }
}

// Round 6
// 1277.588 us; speedup vs baseline: 2.2227x; 1.0239x over previous
//
#include <hip/hip_runtime.h>
#include <hip/hip_bf16.h>

// Round 6: round-5 structure with the tier-1 host bug fixed.
// Bug: expert-1's conv_wd2 pack was launched at WP + 16*KT2*8192 shorts (45 MB)
// but the expert stride down4 reads is 16*KT2*16384 shorts (90 MB) — expert-1's
// tiles overwrote expert-0's nb>=8 tiles and left expert-1 reading garbage.
// Fix: correct expert-1 offset. Kernels unchanged from round 5 (ledgers audited).
//
// gu4 = 2 fat phases/K-tile (32 MFMA, 12 ds_read, 4 barriers/K-tile), counted vmcnt(4).
// down4 = both experts, 256x256 tile, BK=32 unit-steps, ring-3 LDS (96KB),
//   1 phase/step (32 MFMA, 12 ds_read, 2 barriers/step), loads issued 2 steps ahead.
// Packed-unit format: unit = 256 rows x 32 k bf16 (16 KB), elem (r,k) at short-offset
//   q*64 + pos*8 + (k&7), q=r>>1, pos=(((r&1)<<2)|((k>>3)&3))^(q&7).

#define HDIM 4096
#define IDIM 11008
#define N2   22016
#define MTOK 2048
#define KT1  64      // HDIM/64
#define KT2  172     // IDIM/64
#define NB1  86      // IDIM/128
#define NB2  32      // HDIM/128
#define NKD  344     // 2*KT2: down K-steps of 32

typedef unsigned short ushort_t;
using f32x4  = __attribute__((ext_vector_type(4))) float;
using bf16x8 = __attribute__((ext_vector_type(8))) short;
using u32x2  = __attribute__((ext_vector_type(2))) unsigned int;
using u32x4  = __attribute__((ext_vector_type(4))) unsigned int;

__device__ __forceinline__ unsigned int bf16rne(float f) {
    unsigned int u = __builtin_bit_cast(unsigned int, f);
    return (u + 0x7FFFu + ((u >> 16) & 1u)) >> 16;
}
__device__ __forceinline__ unsigned int pack2(float lo, float hi) {
    return bf16rne(lo) | (bf16rne(hi) << 16);
}
__device__ __forceinline__ void gl_lds16(const void* g, void* l) {
    __builtin_amdgcn_global_load_lds(
        (const __attribute__((address_space(1))) void*)g,
        (__attribute__((address_space(3))) void*)l, 16, 0, 0);
}

// ---------------- conversion kernels (fp32 -> packed bf16 units) ----------------

// x [2048][4096] -> XP [mb256(8)][kt(64)] 32KB tiles ([ks0 unit][ks1 unit])
__global__ __launch_bounds__(256)
void conv_x(const float* __restrict__ X, ushort_t* __restrict__ XP) {
    int bid = blockIdx.x;               // 16 mb128 * 64 kt
    int mb = bid >> 6, kt = bid & 63;
    int t = threadIdx.x;
    int r0 = t >> 4, c4 = t & 15;
    int kh = c4 >> 3, c = (c4 >> 1) & 3, lo4 = (c4 & 1) << 2;
    ushort_t* tp = XP + ((long)(mb >> 1) * KT1 + kt) * 16384 + (long)kh * 8192 + (mb & 1) * 4096;
#pragma unroll
    for (int p = 0; p < 8; ++p) {
        int rl = r0 + p * 16;
        f32x4 v = *(const f32x4*)(X + (long)(mb * 128 + rl) * HDIM + kt * 64 + c4 * 4);
        u32x2 pk = { pack2(v[0], v[1]), pack2(v[2], v[3]) };
        int q = rl >> 1;
        int pos = ((((rl & 1) << 2) | c) ^ (q & 7));
        *(u32x2*)&tp[q * 64 + pos * 8 + lo4] = pk;
    }
}

// Wgu [4096][22016] -> WP [(nb*64+kt)] 32KB tiles: [kh][g 4KB-sh | u 4KB-sh]
__global__ __launch_bounds__(256)
void conv_wgu(const float* __restrict__ W, ushort_t* __restrict__ WP) {
    int bid = blockIdx.x;               // nb(86)*kt(64)*e(2)
    int e = bid & 1, kt = (bid >> 1) & 63, nb = bid >> 7;
    int t = threadIdx.x;
    int kp = t >> 5, c4 = t & 31;
    const float* p = W + ((long)kt * 64 + kp * 8) * N2 + (long)e * IDIM + nb * 128 + c4 * 4;
    f32x4 v[8];
#pragma unroll
    for (int j = 0; j < 8; ++j) v[j] = *(const f32x4*)(p + (long)j * N2);
    ushort_t* tp = WP + ((long)nb * KT1 + kt) * 16384 + (long)(kp >> 2) * 8192 + e * 4096;
    int c = kp & 3;
#pragma unroll
    for (int cc = 0; cc < 4; ++cc) {
        int n = c4 * 4 + cc;
        int q = n >> 1;
        int pos = ((((n & 1) << 2) | c) ^ (q & 7));
        u32x4 pk = { pack2(v[0][cc], v[1][cc]), pack2(v[2][cc], v[3][cc]),
                     pack2(v[4][cc], v[5][cc]), pack2(v[6][cc], v[7][cc]) };
        *(u32x4*)&tp[q * 64 + pos * 8] = pk;
    }
}

// Wd [11008][4096] -> WPd2 256-col tiles [nb(16)][kt(172)] 32KB ([ks0][ks1]) (tier-1)
__global__ __launch_bounds__(256)
void conv_wd2(const float* __restrict__ W, ushort_t* __restrict__ WPd) {
    int bid = blockIdx.x;               // nb(16)*kt(172)
    int kt = bid % KT2, nb = bid / KT2;
    int t = threadIdx.x;
    int kp = t >> 5, c4 = t & 31;
    ushort_t* tp = WPd + ((long)nb * KT2 + kt) * 16384 + (long)(kp >> 2) * 8192;
    int c = kp & 3;
#pragma unroll
    for (int h = 0; h < 2; ++h) {
        const float* p = W + ((long)kt * 64 + kp * 8) * HDIM + nb * 256 + h * 128 + c4 * 4;
        f32x4 v[8];
#pragma unroll
        for (int j = 0; j < 8; ++j) v[j] = *(const f32x4*)(p + (long)j * HDIM);
#pragma unroll
        for (int cc = 0; cc < 4; ++cc) {
            int n = h * 128 + c4 * 4 + cc;
            int q = n >> 1;
            int pos = ((((n & 1) << 2) | c) ^ (q & 7));
            u32x4 pk = { pack2(v[0][cc], v[1][cc]), pack2(v[2][cc], v[3][cc]),
                         pack2(v[4][cc], v[5][cc]), pack2(v[6][cc], v[7][cc]) };
            *(u32x4*)&tp[q * 64 + pos * 8] = pk;
        }
    }
}

// Wd -> 128-col tiles [nb(32)][kt(172)] 16KB (tier-2 / down3)
__global__ __launch_bounds__(256)
void conv_wd(const float* __restrict__ W, ushort_t* __restrict__ WP) {
    int bid = blockIdx.x;               // nb(32)*kt(172)
    int kt = bid % KT2, nb = bid / KT2;
    int t = threadIdx.x;
    int kp = t >> 5, c4 = t & 31;
    const float* p = W + ((long)kt * 64 + kp * 8) * HDIM + nb * 128 + c4 * 4;
    f32x4 v[8];
#pragma unroll
    for (int j = 0; j < 8; ++j) v[j] = *(const f32x4*)(p + (long)j * HDIM);
    ushort_t* tp = WP + ((long)nb * KT2 + kt) * 8192 + (long)(kp >> 2) * 4096;
    int c = kp & 3;
#pragma unroll
    for (int cc = 0; cc < 4; ++cc) {
        int n = c4 * 4 + cc;
        int q = n >> 1;
        int pos = ((((n & 1) << 2) | c) ^ (q & 7));
        u32x4 pk = { pack2(v[0][cc], v[1][cc]), pack2(v[2][cc], v[3][cc]),
                     pack2(v[4][cc], v[5][cc]), pack2(v[6][cc], v[7][cc]) };
        *(u32x4*)&tp[q * 64 + pos * 8] = pk;
    }
}

// stage one 16KB unit (8192 shorts): 2 x global_load_lds per thread, linear dest
#define STAGE_U(SRC, DSTOFF) do { \
    gl_lds16((SRC) + so + lane * 8, &lds[(DSTOFF) + so]); \
    gl_lds16((SRC) + 4096 + so + lane * 8, &lds[(DSTOFF) + 4096 + so]); } while (0)

#define MFMA16(ACC, AF, BF) \
    _Pragma("unroll") \
    for (int mf = 0; mf < 4; ++mf) \
        _Pragma("unroll") \
        for (int nf = 0; nf < 4; ++nf) \
            ACC[mf][nf] = __builtin_amdgcn_mfma_f32_16x16x32_bf16(AF[mf], BF[nf], ACC[mf][nf], 0, 0, 0);

#define VMCNT_MID(N) do { \
    if (pf) asm volatile("s_waitcnt vmcnt(" #N ")" ::: "memory"); \
    else    asm volatile("s_waitcnt vmcnt(0)" ::: "memory"); } while (0)
#define VMCNT_END(N) do { \
    if (pf) asm volatile("s_waitcnt vmcnt(" #N ")" ::: "memory"); } while (0)

// ---------------- GEMM1: fused gate/up + silu, 2 fat phases per K-tile ----------------
__global__ __launch_bounds__(512, 2)
void gu4_kernel(const ushort_t* __restrict__ XP, const ushort_t* __restrict__ WP,
                ushort_t* __restrict__ HP) {
    __shared__ ushort_t lds[65536];     // [2 buf][A0 | A1 | B0(g|u) | B1(g|u)]
    int nwg = gridDim.x;                // 688
    int cpx = nwg >> 3;
    int sw  = (blockIdx.x & 7) * cpx + (blockIdx.x >> 3);
    int mblk = sw & 7;                  // 0..7
    int nblk = sw >> 3;                 // 0..85
    const int t = threadIdx.x, lane = t & 63, w = t >> 6;
    const int wr = w >> 1, wc = w & 1;  // 4M x 2N waves
    const int rr = lane & 15, g4 = lane >> 4;
    const int so = w * 512;

    int aoff[4], boff[4];
#pragma unroll
    for (int mf = 0; mf < 4; ++mf) {
        int m = wr * 64 + mf * 16 + rr, q = m >> 1;
        aoff[mf] = q * 64 + ((((((m & 1) << 2) | g4) ^ (q & 7))) << 3);
    }
#pragma unroll
    for (int nf = 0; nf < 4; ++nf) {
        int n = wc * 64 + nf * 16 + rr, q = n >> 1;
        boff[nf] = q * 64 + ((((((n & 1) << 2) | g4) ^ (q & 7))) << 3);
    }

    f32x4 accg[4][4] = {}, accu[4][4] = {};
    const ushort_t* srcA = XP + (long)mblk * KT1 * 16384;
    const ushort_t* srcB = WP + (long)nblk * KT1 * 16384;

    // prologue: full tile 0 into buf0
    STAGE_U(srcA, 0);
    STAGE_U(srcB, 16384);
    STAGE_U(srcA + 8192, 8192);
    STAGE_U(srcB + 8192, 24576);
    asm volatile("s_waitcnt vmcnt(0)" ::: "memory");
    __builtin_amdgcn_s_barrier();

    int cur = 0;
    for (int kt = 0; kt < KT1; ++kt) {
        const int cb = cur * 32768, pb = (cur ^ 1) * 32768;
        const ushort_t* nA = srcA + (long)(kt + 1) * 16384;
        const ushort_t* nB = srcB + (long)(kt + 1) * 16384;
        const bool pf = (kt + 1 < KT1);
        bf16x8 af[4], bg[4], bu[4];

        // ---- phase 0: ks0, gate+up (32 MFMA) ----
#pragma unroll
        for (int mf = 0; mf < 4; ++mf) af[mf] = *(const bf16x8*)&lds[cb + aoff[mf]];
#pragma unroll
        for (int nf = 0; nf < 4; ++nf) {
            bg[nf] = *(const bf16x8*)&lds[cb + 16384 + boff[nf]];
            bu[nf] = *(const bf16x8*)&lds[cb + 16384 + 4096 + boff[nf]];
        }
        if (pf) { STAGE_U(nA, pb); STAGE_U(nB, pb + 16384); }
        __builtin_amdgcn_s_barrier();
        __builtin_amdgcn_s_setprio(1);
        MFMA16(accg, af, bg);
        MFMA16(accu, af, bu);
        __builtin_amdgcn_s_setprio(0);
        VMCNT_MID(4);                       // lands A1,B1 of cur tile; full drain on tail
        __builtin_amdgcn_s_barrier();

        // ---- phase 1: ks1, gate+up ----
#pragma unroll
        for (int mf = 0; mf < 4; ++mf) af[mf] = *(const bf16x8*)&lds[cb + 8192 + aoff[mf]];
#pragma unroll
        for (int nf = 0; nf < 4; ++nf) {
            bg[nf] = *(const bf16x8*)&lds[cb + 24576 + boff[nf]];
            bu[nf] = *(const bf16x8*)&lds[cb + 24576 + 4096 + boff[nf]];
        }
        if (pf) { STAGE_U(nA + 8192, pb + 8192); STAGE_U(nB + 8192, pb + 24576); }
        __builtin_amdgcn_s_barrier();
        __builtin_amdgcn_s_setprio(1);
        MFMA16(accg, af, bg);
        MFMA16(accu, af, bu);
        __builtin_amdgcn_s_setprio(0);
        VMCNT_END(4);                       // lands A0,B0 of next tile; skip on tail
        __builtin_amdgcn_s_barrier();

        cur ^= 1;
    }

    // epilogue: silu(g)*u -> HP packed tiles
#pragma unroll
    for (int nf = 0; nf < 4; ++nf) {
        int nloc = wc * 64 + nf * 16 + rr;
        int kt2 = nblk * 2 + (nloc >> 6);
        int k = nloc & 63;
        int kh = k >> 5, c = (k >> 3) & 3, klow = k & 7;
        ushort_t* tp = HP + ((long)mblk * KT2 + kt2) * 16384 + kh * 8192 + klow;
#pragma unroll
        for (int mf = 0; mf < 4; ++mf)
#pragma unroll
            for (int i = 0; i < 4; ++i) {
                int m = wr * 64 + mf * 16 + g4 * 4 + i;
                int q = m >> 1;
                int pos = ((((m & 1) << 2) | c) ^ (q & 7));
                float gv = accg[mf][nf][i], uv = accu[mf][nf][i];
                float s = gv / (1.0f + __expf(-gv));
                tp[q * 64 + pos * 8] = (ushort_t)bf16rne(s * uv);
            }
    }
}

// ---------------- GEMM2 tier-1: both experts, 256x256, ring-3, 1 phase/K-32-step ----------------
__global__ __launch_bounds__(512, 2)
void down4_kernel(const ushort_t* __restrict__ HP, const ushort_t* __restrict__ WPd,
                  float* __restrict__ Out) {
    __shared__ ushort_t lds[49152];     // ring-3 x [A-unit 8192 | B-unit 8192]
    int nwg = gridDim.x;                // 256
    int cpx = nwg >> 3;
    int sw  = (blockIdx.x & 7) * cpx + (blockIdx.x >> 3);
    int mblk = sw & 15;                 // 0..15 (expert = mblk>>3)
    int nblk = sw >> 4;                 // 0..15
    const int t = threadIdx.x, lane = t & 63, w = t >> 6;
    const int wr = w >> 2, wc = w & 3;  // 2M x 4N waves, per-wave out 128x64
    const int rr = lane & 15, g4 = lane >> 4;
    const int so = w * 512;

    int aoff[8], boff[4];
#pragma unroll
    for (int mf = 0; mf < 8; ++mf) {
        int m = wr * 128 + mf * 16 + rr, q = m >> 1;
        aoff[mf] = q * 64 + ((((((m & 1) << 2) | g4) ^ (q & 7))) << 3);
    }
#pragma unroll
    for (int nf = 0; nf < 4; ++nf) {
        int n = wc * 64 + nf * 16 + rr, q = n >> 1;
        boff[nf] = q * 64 + ((((((n & 1) << 2) | g4) ^ (q & 7))) << 3);
    }

    f32x4 acc[8][4] = {};
    const ushort_t* srcA = HP  + (long)mblk * KT2 * 16384;                 // unit stream, stride 8192
    const ushort_t* srcB = WPd + (long)(((mblk >> 3) << 4) + nblk) * KT2 * 16384;

    // prologue: stage step 0 -> slot0, step 1 -> slot1
    STAGE_U(srcA, 0);
    STAGE_U(srcB, 8192);
    STAGE_U(srcA + 8192, 16384);
    STAGE_U(srcB + 8192, 16384 + 8192);
    asm volatile("s_waitcnt vmcnt(4)" ::: "memory");   // step0 landed
    __builtin_amdgcn_s_barrier();

    int cb = 0, sb = 32768;             // current slot, stage slot
    for (int kt = 0; kt < NKD; ++kt) {
        bf16x8 af[8], bf[4];
#pragma unroll
        for (int mf = 0; mf < 8; ++mf) af[mf] = *(const bf16x8*)&lds[cb + aoff[mf]];
#pragma unroll
        for (int nf = 0; nf < 4; ++nf) bf[nf] = *(const bf16x8*)&lds[cb + 8192 + boff[nf]];
        const bool pf = (kt + 2 < NKD);
        if (pf) {
            const ushort_t* nA = srcA + (long)(kt + 2) * 8192;
            const ushort_t* nB = srcB + (long)(kt + 2) * 8192;
            STAGE_U(nA, sb);
            STAGE_U(nB, sb + 8192);
        }
        __builtin_amdgcn_s_barrier();
        __builtin_amdgcn_s_setprio(1);
#pragma unroll
        for (int mf = 0; mf < 8; ++mf)
#pragma unroll
            for (int nf = 0; nf < 4; ++nf)
                acc[mf][nf] = __builtin_amdgcn_mfma_f32_16x16x32_bf16(af[mf], bf[nf], acc[mf][nf], 0, 0, 0);
        __builtin_amdgcn_s_setprio(0);
        if (pf)                   asm volatile("s_waitcnt vmcnt(4)" ::: "memory"); // lands step kt+1
        else if (kt + 1 < NKD)    asm volatile("s_waitcnt vmcnt(0)" ::: "memory"); // tail drain
        __builtin_amdgcn_s_barrier();
        sb = cb;
        cb += 16384; if (cb == 49152) cb = 0;
    }

#pragma unroll
    for (int mf = 0; mf < 8; ++mf)
#pragma unroll
        for (int nf = 0; nf < 4; ++nf)
#pragma unroll
            for (int i = 0; i < 4; ++i) {
                int m = mblk * 256 + wr * 128 + mf * 16 + g4 * 4 + i;
                int n = nblk * 256 + wc * 64 + nf * 16 + rr;
                Out[(long)m * HDIM + n] = acc[mf][nf][i];
            }
}

// ---------------- GEMM2 tier-2: per-expert 256x128, 2 phases/K-tile (round-4, proven) ----------------
__global__ __launch_bounds__(512, 2)
void down3_kernel(const ushort_t* __restrict__ HP, const ushort_t* __restrict__ WP,
                  float* __restrict__ Out) {
    __shared__ ushort_t lds[49152];     // [2 buf][A-k0 | A-k1 | B(kh0|kh1)]
    int nwg = gridDim.x;                // 256
    int cpx = nwg >> 3;
    int sw  = (blockIdx.x & 7) * cpx + (blockIdx.x >> 3);
    int mblk = sw & 7;
    int nblk = sw >> 3;                 // 0..31
    const int t = threadIdx.x, lane = t & 63, w = t >> 6;
    const int wr = w >> 1, wc = w & 1;
    const int rr = lane & 15, g4 = lane >> 4;
    const int so = w * 512;

    int aoff[4], boff[4];
#pragma unroll
    for (int mf = 0; mf < 4; ++mf) {
        int m = wr * 64 + mf * 16 + rr, q = m >> 1;
        aoff[mf] = q * 64 + ((((((m & 1) << 2) | g4) ^ (q & 7))) << 3);
    }
#pragma unroll
    for (int nf = 0; nf < 4; ++nf) {
        int n = wc * 64 + nf * 16 + rr, q = n >> 1;
        boff[nf] = q * 64 + ((((((n & 1) << 2) | g4) ^ (q & 7))) << 3);
    }

    f32x4 acc[4][4] = {};
    const ushort_t* srcA = HP + (long)mblk * KT2 * 16384;
    const ushort_t* srcB = WP + (long)nblk * KT2 * 8192;

    STAGE_U(srcA, 0);
    STAGE_U(srcA + 8192, 8192);
    STAGE_U(srcB, 16384);
    asm volatile("s_waitcnt vmcnt(0)" ::: "memory");
    __builtin_amdgcn_s_barrier();

    int cur = 0;
    for (int kt = 0; kt < KT2; ++kt) {
        const int cb = cur * 24576, pb = (cur ^ 1) * 24576;
        const ushort_t* nA = srcA + (long)(kt + 1) * 16384;
        const ushort_t* nB = srcB + (long)(kt + 1) * 8192;
        const bool pf = (kt + 1 < KT2);
        bf16x8 af[4], bfr[4];

#pragma unroll
        for (int mf = 0; mf < 4; ++mf) af[mf] = *(const bf16x8*)&lds[cb + aoff[mf]];
#pragma unroll
        for (int nf = 0; nf < 4; ++nf) bfr[nf] = *(const bf16x8*)&lds[cb + 16384 + boff[nf]];
        if (pf) { STAGE_U(nA, pb); STAGE_U(nB, pb + 16384); }
        __builtin_amdgcn_s_barrier();
        __builtin_amdgcn_s_setprio(1);
        MFMA16(acc, af, bfr);
        __builtin_amdgcn_s_setprio(0);
        VMCNT_MID(4);
        __builtin_amdgcn_s_barrier();

#pragma unroll
        for (int mf = 0; mf < 4; ++mf) af[mf] = *(const bf16x8*)&lds[cb + 8192 + aoff[mf]];
#pragma unroll
        for (int nf = 0; nf < 4; ++nf) bfr[nf] = *(const bf16x8*)&lds[cb + 20480 + boff[nf]];
        if (pf) STAGE_U(nA + 8192, pb + 8192);
        __builtin_amdgcn_s_barrier();
        __builtin_amdgcn_s_setprio(1);
        MFMA16(acc, af, bfr);
        __builtin_amdgcn_s_setprio(0);
        VMCNT_END(2);
        __builtin_amdgcn_s_barrier();

        cur ^= 1;
    }

#pragma unroll
    for (int mf = 0; mf < 4; ++mf)
#pragma unroll
        for (int nf = 0; nf < 4; ++nf)
#pragma unroll
            for (int i = 0; i < 4; ++i) {
                int m = mblk * 256 + wr * 64 + mf * 16 + g4 * 4 + i;
                int n = nblk * 128 + wc * 64 + nf * 16 + rr;
                Out[(long)m * HDIM + n] = acc[mf][nf][i];
            }
}

// ================= host =================
extern "C" void kernel_launch(void* const* d_in, const int* in_sizes, int n_in,
                              void* d_out, int out_size, void* d_ws, size_t ws_size,
                              hipStream_t stream) {
    const float* x     = (const float*)d_in[0];
    const float* Wgu_l = (const float*)d_in[3];
    const float* Wd_l  = (const float*)d_in[4];
    const float* Wgu_v = (const float*)d_in[5];
    const float* Wd_v  = (const float*)d_in[6];
    float* out         = (float*)d_out;

    const size_t XP_B  = (size_t)8 * KT1 * 32768;        //  16.8 MB
    const size_t HP_B  = (size_t)8 * KT2 * 32768;        //  45.1 MB (one expert)
    const size_t WP_B  = (size_t)NB1 * KT1 * 32768;      // 180.4 MB (== both Wd-256 packs)
    const size_t NEED1 = XP_B + 2 * HP_B + WP_B;         // 287.4 MB
    const size_t WD2_STRIDE = (size_t)16 * KT2 * 16384;  // expert stride in SHORTS (90.2 MB)

    if (ws_size >= NEED1) {
        ushort_t* XP = (ushort_t*)d_ws;
        ushort_t* HP = XP + XP_B / 2;                    // both experts: HP + e*HP_B/2
        ushort_t* WP = HP + HP_B;                        // after 2*HP_B bytes
        for (int e = 0; e < 2; ++e) {
            const float* xe = x + (long)e * MTOK * HDIM;
            conv_x  <<<dim3(16 * KT1),      dim3(256), 0, stream>>>(xe, XP);
            conv_wgu<<<dim3(NB1 * KT1 * 2), dim3(256), 0, stream>>>(e ? Wgu_v : Wgu_l, WP);
            gu4_kernel<<<dim3(8 * NB1),     dim3(512), 0, stream>>>(XP, WP, HP + (size_t)e * (HP_B / 2));
        }
        // repack Wd (both experts) into WP region at the stride down4 reads
        conv_wd2<<<dim3(16 * KT2), dim3(256), 0, stream>>>(Wd_l, WP);
        conv_wd2<<<dim3(16 * KT2), dim3(256), 0, stream>>>(Wd_v, WP + WD2_STRIDE);
        down4_kernel<<<dim3(256), dim3(512), 0, stream>>>(HP, WP, out);
    } else {
        // tier-2: round-4 proven flow (ws >= 242.2 MB)
        ushort_t* XP = (ushort_t*)d_ws;
        ushort_t* HP = XP + XP_B / 2;
        ushort_t* WP = HP + HP_B / 2;
        for (int e = 0; e < 2; ++e) {
            const float* xe = x + (long)e * MTOK * HDIM;
            float*       oe = out + (long)e * MTOK * HDIM;
            conv_x  <<<dim3(16 * KT1),      dim3(256), 0, stream>>>(xe, XP);
            conv_wgu<<<dim3(NB1 * KT1 * 2), dim3(256), 0, stream>>>(e ? Wgu_v : Wgu_l, WP);
            gu4_kernel<<<dim3(8 * NB1),     dim3(512), 0, stream>>>(XP, WP, HP);
            conv_wd <<<dim3(NB2 * KT2),     dim3(256), 0, stream>>>(e ? Wd_v : Wd_l, WP);
            down3_kernel<<<dim3(8 * NB2),   dim3(512), 0, stream>>>(HP, WP, oe);
        }
    }
}